// Round 1
// 199.614 us; speedup vs baseline: 1.2905x; 1.2905x over previous
//
#include <hip/hip_runtime.h>
#include <math.h>

#define NPAIR 131072          // 8192 freqs x 16 channels
#define STEPS 19
#define VMD_BLOCKS 256        // x 512 threads = NPAIR
#define ND_BANKS 16

// XOR swizzle: spreads strided radix-8 writes across banks; keeps contiguous free
#define SW(a) ((a) ^ (((a) >> 5) & 31))

#define LD_RLX(p)    __hip_atomic_load((p),       __ATOMIC_RELAXED, __HIP_MEMORY_SCOPE_AGENT)
#define ST_RLX(p,v)  __hip_atomic_store((p),(v),  __ATOMIC_RELAXED, __HIP_MEMORY_SCOPE_AGENT)
#define FAA_RLX(p,v) __hip_atomic_fetch_add((p),(v),__ATOMIC_RELAXED, __HIP_MEMORY_SCOPE_AGENT)

__device__ __forceinline__ float2 cadd(float2 a, float2 b){ return make_float2(a.x+b.x, a.y+b.y); }
__device__ __forceinline__ float2 csub(float2 a, float2 b){ return make_float2(a.x-b.x, a.y-b.y); }
__device__ __forceinline__ float2 cmul(float2 a, float2 b){
    return make_float2(a.x*b.x - a.y*b.y, a.x*b.y + a.y*b.x);
}
template<int SGN>
__device__ __forceinline__ float2 imul(float2 a){   // multiply by e^{SGN*i*pi/2}
    return (SGN > 0) ? make_float2(-a.y, a.x) : make_float2(a.y, -a.x);
}

// 8-point DFT: y_k = sum_r a_r e^{SGN*2pi i r k/8}
template<int SGN>
__device__ __forceinline__ void dft8(const float2* a, float2* y){
    const float C = 0.70710678118654752f;
    const float sg = (SGN > 0) ? 1.f : -1.f;
    float2 t0 = cadd(a[0], a[4]), t1 = csub(a[0], a[4]);
    float2 t2 = cadd(a[2], a[6]), t3 = imul<SGN>(csub(a[2], a[6]));
    float2 E0 = cadd(t0, t2), E2 = csub(t0, t2), E1 = cadd(t1, t3), E3 = csub(t1, t3);
    float2 s0 = cadd(a[1], a[5]), s1 = csub(a[1], a[5]);
    float2 s2 = cadd(a[3], a[7]), s3 = imul<SGN>(csub(a[3], a[7]));
    float2 O0 = cadd(s0, s2), O2 = csub(s0, s2), O1 = cadd(s1, s3), O3 = csub(s1, s3);
    float2 w1 = make_float2(C, sg * C), w3 = make_float2(-C, sg * C);
    float2 R0 = O0, R1 = cmul(O1, w1), R2 = imul<SGN>(O2), R3 = cmul(O3, w3);
    y[0] = cadd(E0, R0); y[4] = csub(E0, R0);
    y[1] = cadd(E1, R1); y[5] = csub(E1, R1);
    y[2] = cadd(E2, R2); y[6] = csub(E2, R2);
    y[3] = cadd(E3, R3); y[7] = csub(E3, R3);
}

// ===== in-LDS 8192-pt Stockham FFT: 4 radix-8 passes + 1 radix-2, 1024 threads =====
template<int SGN>
__device__ void lds_fft8192_r8(float2* lds, int tid){
    #pragma unroll
    for (int pi = 0; pi < 4; pi++){
        int ls = 3 * pi;
        int s  = 1 << ls;
        int nn = 8192 >> ls;
        int q = tid & (s - 1);
        float2 a[8], y[8];
        #pragma unroll
        for (int r = 0; r < 8; r++) a[r] = lds[SW(tid + (r << 10))];
        __syncthreads();
        dft8<SGN>(a, y);
        int p = tid >> ls;
        float ang = (float)(2 * p) / (float)nn;
        float sn, cs;
        sincospif(SGN > 0 ? ang : -ang, &sn, &cs);   // w = e^{SGN*2pi i p/nn}
        float2 w = make_float2(cs, sn);
        float2 wk = make_float2(1.f, 0.f);
        int o = q + ((tid - q) << 3);                 // q + 8*s*p
        lds[SW(o)] = y[0];
        #pragma unroll
        for (int k = 1; k < 8; k++){
            wk = cmul(wk, w);
            lds[SW(o + (k << ls))] = cmul(y[k], wk);
        }
        __syncthreads();
    }
    #pragma unroll
    for (int w4 = 0; w4 < 4; w4++){                   // final radix-2, twiddle-free
        int idx = (w4 << 10) + tid;
        float2 a = lds[SW(idx)], b = lds[SW(idx + 4096)];
        lds[SW(idx)]        = cadd(a, b);
        lds[SW(idx + 4096)] = csub(a, b);
    }
    __syncthreads();
}

// ===== stage A: mirror-extend + FFT16384 (split radix via 2x FFT8192) -> FPT =====
__global__ __launch_bounds__(1024) void k_stageA(const float* __restrict__ sig,
                                                 float2* __restrict__ FPT){
    extern __shared__ float2 lds[];
    int tid = threadIdx.x;
    int cw  = blockIdx.x;
    int cs  = (cw + 8) & 15;                 // fftshift over channel axis
    const float* sp = sig + cs * 8192;
    float2 regA[8];
    #pragma unroll
    for (int r = 0; r < 8; r++){             // even samples of mirrored extension
        int p = r * 1024 + tid;
        int x = 2 * p;
        int mx = (x < 4096) ? (4095 - x) : ((x < 12288) ? (x - 4096) : (20479 - x));
        lds[SW(p)] = make_float2(sp[mx], 0.f);
    }
    __syncthreads();
    lds_fft8192_r8<-1>(lds, tid);
    #pragma unroll
    for (int r = 0; r < 8; r++) regA[r] = lds[SW(r * 1024 + tid)];
    __syncthreads();
    #pragma unroll
    for (int r = 0; r < 8; r++){             // odd samples
        int p = r * 1024 + tid;
        int x = 2 * p + 1;
        int mx = (x < 4096) ? (4095 - x) : ((x < 12288) ? (x - 4096) : (20479 - x));
        lds[SW(p)] = make_float2(sp[mx], 0.f);
    }
    __syncthreads();
    lds_fft8192_r8<-1>(lds, tid);
    // combine: F[j] = A[j] + e^{-i pi j/8192} B[j]
    float sn, cn;
    sincospif(-(float)tid / 8192.0f, &sn, &cn);
    float2 w = make_float2(cn, sn);
    const float2 Wst = make_float2(0.92387953251128674f, -0.38268343236508977f); // e^{-i pi/8}
    #pragma unroll
    for (int q = 0; q < 8; q++){
        int j = q * 1024 + tid;
        float2 B = lds[SW(j)];
        float2 t = cmul(B, w);
        FPT[cw * 8192 + j] = make_float2(regA[q].x + t.x, regA[q].y + t.y);
        w = cmul(w, Wst);
    }
}

// ===== fused 19-step VMD: FULLY-RELAXED LLC barrier (no acquire/release anywhere) ====
// Theory (R16): all cross-block data (NDB sums, counters, flags) moves through
// AGENT-scope atomics, which execute at the LLC (bypassing non-coherent per-XCD
// L2). LLC completion order IS the visibility order -> no fences needed.
// Proven pieces kept: 512-thr blocks (72 VGPR, no spill — R13/14: 1024-thr caps
// VGPR at 64 -> 28-reg spill -> 50 MB scratch); relaxed polls (R11); no O(N)
// serial leader work (R12); banked NDB (R9).
// R17 (this round): the 96 double-shuffles/step (=192 ds_bpermute_b32) were
// ~1536 DS ops/CU/step ≈ 3.2 us/step on the shared per-CU LDS pipe — invisible
// in VALUBusy (19%). Replaced with a role-splitting multi-value butterfly:
// at each level the two lane halves swap complementary halves of the value
// set (cndmask select, 1 exchange), halving live values per level:
// 8+4+2+1 dbl-shfls over xor{32,16,8,4} + 2 final over xor{2,1} = 17 dbl-shfls
// (34 b32 DS ops, 5.6x fewer). Lane l ends holding the full wave sum for
// idx = l>>2 (idx<8: n_k, idx>=8: d_k) — drops into the existing lred layout.
__global__ __launch_bounds__(512, 2) void k_vmd_all(const float2* __restrict__ FPT,
                                                    float2* __restrict__ U,
                                                    double* __restrict__ D){
    double* NDB = D;
    int*    CNT = (int*)(D + 4864);

    int tid = blockIdx.x * 512 + threadIdx.x;   // [0,NPAIR), tid = cw*8192+j
    int j = tid & 8191;
    double fr = (double)j / 16384.0;
    float2 fv = FPT[tid];
    double fx = fv.x, fy = fv.y;
    float urx[8], ury[8];
    double om[8];
    #pragma unroll
    for (int k = 0; k < 8; k++){ urx[k] = 0.f; ury[k] = 0.f; om[k] = 0.0625 * (double)k; }
    __shared__ double lred[8][16];
    __shared__ double ndls[256];
    __shared__ double om_s[8];
    int lane = threadIdx.x & 63, wv = threadIdx.x >> 6;
    int mybank = (blockIdx.x & (ND_BANKS - 1)) * 16;
    int grp = blockIdx.x >> 4;                  // 16 groups of 16 blocks

    for (int step = 0; step < STEPS; step++){
        if (step > 0){
            #pragma unroll
            for (int k = 0; k < 8; k++) om[k] = om_s[k];
        }
        double sx = 0.0, sy = 0.0;
        #pragma unroll
        for (int k = 1; k < 8; k++){ sx += (double)urx[k]; sy += (double)ury[k]; }
        double lx = 0.0, ly = 0.0, nloc[8], dloc[8];
        #pragma unroll
        for (int k = 0; k < 8; k++){
            if (k > 0){ sx += lx - (double)urx[k]; sy += ly - (double)ury[k]; }
            double d = fr - om[k];
            double den = 1.0 + 2000.0 * d * d;
            double nx = (fx - sx) / den, ny = (fy - sy) / den;
            urx[k] = (float)nx; ury[k] = (float)ny;   // replicate complex64 carry
            lx = nx; ly = ny;
            double pw = nx * nx + ny * ny;
            nloc[k] = fr * pw; dloc[k] = pw;
        }
        // ---- multi-value butterfly reduce: 16 doubles across 64 lanes, 17 dbl-shfls ----
        // Level A (xor 32): bit5=0 lanes keep n-values, bit5=1 keep d-values.
        double s8[8];
        {
            bool hi = (lane & 32) != 0;
            #pragma unroll
            for (int k = 0; k < 8; k++){
                double t = hi ? nloc[k] : dloc[k];          // what we give away
                double r = __shfl_xor(t, 32);
                s8[k] = (hi ? dloc[k] : nloc[k]) + r;       // what we keep
            }
        }
        // Level B (xor 16): bit4=0 keeps idx 0..3, bit4=1 keeps idx 4..7.
        double s4v[4];
        {
            bool hi = (lane & 16) != 0;
            #pragma unroll
            for (int k = 0; k < 4; k++){
                double t = hi ? s8[k] : s8[k + 4];
                double r = __shfl_xor(t, 16);
                s4v[k] = (hi ? s8[k + 4] : s8[k]) + r;
            }
        }
        // Level C (xor 8)
        double s2v[2];
        {
            bool hi = (lane & 8) != 0;
            #pragma unroll
            for (int k = 0; k < 2; k++){
                double t = hi ? s4v[k] : s4v[k + 2];
                double r = __shfl_xor(t, 8);
                s2v[k] = (hi ? s4v[k + 2] : s4v[k]) + r;
            }
        }
        // Level D (xor 4)
        double sv;
        {
            bool hi = (lane & 4) != 0;
            double t = hi ? s2v[0] : s2v[1];
            double r = __shfl_xor(t, 4);
            sv = (hi ? s2v[1] : s2v[0]) + r;
        }
        // Final two full butterflies over the remaining 4-lane replication group
        sv += __shfl_xor(sv, 2);
        sv += __shfl_xor(sv, 1);
        // lane l holds wave-total for idx = l>>2 (idx<8: n_idx, idx>=8: d_{idx-8})
        if ((lane & 3) == 0) lred[wv][lane >> 2] = sv;
        __syncthreads();
        if (threadIdx.x < 16){
            double sum = 0.0;
            #pragma unroll
            for (int w = 0; w < 8; w++) sum += lred[w][threadIdx.x];
            atomicAdd(&NDB[step * 256 + mybank + threadIdx.x], sum);  // LLC f64 atomic
        }
        __syncthreads();      // wave0 vmcnt drained -> NDB adds COMPLETE at LLC
        if (step < STEPS - 1){
            if (threadIdx.x == 0){
                int target = 16 * (step + 1);   // monotonic counters: no reset race
                int old = FAA_RLX(&CNT[grp * 32], 1);
                if (old == target - 1){         // group-last
                    int rold = FAA_RLX(&CNT[512], 1);
                    if (rold == target - 1){    // root-last: publish release flag
                        ST_RLX(&CNT[544], step + 1);
                    } else {                    // other group-lasts: wait on root flag
                        while (LD_RLX(&CNT[544]) <= step)
                            __builtin_amdgcn_s_sleep(1);
                    }
                    // fan-out: 16 relaxed stores happen IN PARALLEL across group-lasts
                    ST_RLX(&CNT[576 + grp * 32], step + 1);
                } else {                        // members: wait on own group flag
                    while (LD_RLX(&CNT[576 + grp * 32]) <= step)
                        __builtin_amdgcn_s_sleep(1);
                }
            }
            __syncthreads();
            // parallel readback: 256 threads fetch one double each (LLC), sum in LDS
            if (threadIdx.x < 256)
                ndls[threadIdx.x] = LD_RLX(&NDB[step * 256 + threadIdx.x]);
            __syncthreads();
            if (threadIdx.x < 8){
                double n_ = 0.0, d_ = 0.0;
                #pragma unroll
                for (int bk = 0; bk < ND_BANKS; bk++){
                    n_ += ndls[bk * 16 + threadIdx.x];
                    d_ += ndls[bk * 16 + 8 + threadIdx.x];
                }
                om_s[threadIdx.x] = n_ / d_;
            }
            __syncthreads();
        }
    }
    #pragma unroll
    for (int k = 0; k < 8; k++) U[k * NPAIR + tid] = make_float2(urx[k], ury[k]);
}

// ===== stage C+D: hermitian iFFT16384 -> slice -> FFT8192; results into own U slice =====
// After: U32[b*16384 + t] = y[t];  U32[b*16384 + 8192 + t] = Re(Yf[(t+4096) mod 8192])
__global__ __launch_bounds__(1024) void k_stageCD(float2* __restrict__ U){
    extern __shared__ float2 lds[];
    int tid = threadIdx.x;
    int b = blockIdx.x;                      // b = k*16 + cw
    const float2* pos = U + b * 8192;
    float* slice = (float*)(U) + (size_t)b * 16384;
    const float inv = 1.0f / 16384.0f;
    float2 regA[8];
    #pragma unroll
    for (int r = 0; r < 8; r++){             // v_even[p] = v[2p] (hermitian map)
        int p = r * 1024 + tid;
        int m = 2 * p;
        int jj; bool cj;
        if (m == 0)          { jj = 0;         cj = true;  }
        else if (m <= 8191)  { jj = m;         cj = false; }
        else if (m == 8192)  { jj = 8191;      cj = true;  }
        else                 { jj = 16384 - m; cj = true;  }
        float2 pv = pos[jj];
        lds[SW(p)] = make_float2(pv.x, cj ? -pv.y : pv.y);
    }
    __syncthreads();
    lds_fft8192_r8<1>(lds, tid);
    #pragma unroll
    for (int r = 0; r < 8; r++) regA[r] = lds[SW(r * 1024 + tid)];
    __syncthreads();
    #pragma unroll
    for (int r = 0; r < 8; r++){             // v_odd[p] = v[2p+1]
        int p = r * 1024 + tid;
        int m = 2 * p + 1;
        int jj; bool cj;
        if (m <= 8191) { jj = m;         cj = false; }
        else           { jj = 16384 - m; cj = true;  }
        float2 pv = pos[jj];
        lds[SW(p)] = make_float2(pv.x, cj ? -pv.y : pv.y);
    }
    __syncthreads();
    lds_fft8192_r8<1>(lds, tid);
    // combine -> y[t], coalesced write into own slice (all pos reads done)
    float yreg[8];
    float sn, cn;
    sincospif((float)(4096 + tid) / 8192.0f, &sn, &cn);
    float2 w = make_float2(cn, sn);
    const float2 Wst = make_float2(0.92387953251128674f, 0.38268343236508977f);  // e^{+i pi/8}
    #pragma unroll
    for (int q = 0; q < 8; q++){
        int t = q * 1024 + tid;
        int r = (q + 4) & 7;                 // (t+4096) mod 8192 block
        float2 A = regA[r];
        float2 B = lds[SW(r * 1024 + tid)];
        float2 tw = cmul(B, w);
        float yv = (A.x + tw.x) * inv;
        yreg[q] = yv;
        slice[t] = yv;
        w = cmul(w, Wst);
    }
    __syncthreads();
    #pragma unroll
    for (int q = 0; q < 8; q++) lds[SW(q * 1024 + tid)] = make_float2(yreg[q], 0.f);
    __syncthreads();
    lds_fft8192_r8<-1>(lds, tid);            // forward FFT8192 of y
    #pragma unroll
    for (int q = 0; q < 8; q++){
        int t = q * 1024 + tid;
        float2 Y = lds[SW(((q + 4) & 7) * 1024 + tid)];
        slice[8192 + t] = Y.x;               // Re(Yf[(t+4096) mod 8192]), coalesced
    }
}

// ===== transpose 1: out0[(k*8192+t)*16 + ch] = y[k*16+cw][t], ch=(cw+8)&15 =====
__global__ __launch_bounds__(256) void k_out0T(const float* __restrict__ U32,
                                               float* __restrict__ out){
    __shared__ float tile[16][257];
    int tid = threadIdx.x;
    int k  = blockIdx.y;
    int t0 = blockIdx.x * 256;
    #pragma unroll
    for (int cw = 0; cw < 16; cw++)
        tile[cw][tid] = U32[((size_t)(k * 16 + cw)) * 16384 + t0 + tid];
    __syncthreads();
    #pragma unroll
    for (int i = 0; i < 16; i++){
        int flat = i * 256 + tid;            // flat = dt*16 + ch
        int dt = flat >> 4, ch = flat & 15;
        int cw = (ch + 8) & 15;
        out[(size_t)k * 131072 + t0 * 16 + flat] = tile[cw][dt];
    }
}

// ===== transpose 2: out1[1048576 + t*128 + b] = W2[b][t] =====
__global__ __launch_bounds__(256) void k_out1T(const float* __restrict__ U32,
                                               float* __restrict__ out){
    __shared__ float tile[128][65];
    int tid = threadIdx.x;
    int t0 = blockIdx.x * 64;
    #pragma unroll
    for (int i = 0; i < 32; i++){
        int flat = i * 256 + tid;
        int b = flat >> 6, dt = flat & 63;
        tile[b][dt] = U32[(size_t)b * 16384 + 8192 + t0 + dt];
    }
    __syncthreads();
    #pragma unroll
    for (int i = 0; i < 32; i++){
        int flat = i * 256 + tid;
        int dt = flat >> 7, b = flat & 127;
        out[1048576 + (size_t)(t0 + dt) * 128 + b] = tile[b][dt];
    }
}

// ===== omega history: out2 = Re(omega), 160 floats at 2097152 =====
__global__ void k_omega(const double* __restrict__ ndb, float* __restrict__ out){
    int t = threadIdx.x;
    if (t >= 160) return;
    int row = t >> 3, k = t & 7;
    double v;
    if (row == 0){
        v = 0.0625 * (double)k;
    } else {
        const double* r = ndb + (row - 1) * 256;
        double n_ = 0.0, d_ = 0.0;
        #pragma unroll
        for (int bk = 0; bk < ND_BANKS; bk++){ n_ += r[bk * 16 + k]; d_ += r[bk * 16 + 8 + k]; }
        v = n_ / d_;
    }
    out[2097152 + t] = (float)v;
}

__global__ void k_zerond(double* __restrict__ q, int n){
    int i = blockIdx.x * blockDim.x + threadIdx.x;
    if (i < n) q[i] = 0.0;
}

extern "C" void kernel_launch(void* const* d_in, const int* in_sizes, int n_in,
                              void* d_out, int out_size, void* d_ws, size_t ws_size,
                              hipStream_t stream){
    const float* sig = (const float*)d_in[0];
    float* out = (float*)d_out;
    char* p = (char*)d_ws;
    // ws: U 8 MB | FPT 1 MB | D (NDB banks + CNT/flags) ~43 KB  (~9.05 MB total)
    float2* U   = (float2*)p;
    float2* FPT = (float2*)(p + (size_t)8 * 1024 * 1024);
    double* D   = (double*)(p + (size_t)9 * 1024 * 1024);

    // zero NDB D[0..4864) + full CNT/flag span D[4864..5400)
    k_zerond<<<dim3(22), dim3(256), 0, stream>>>(D, 5400);
    k_stageA<<<dim3(16), dim3(1024), 65536, stream>>>(sig, FPT);
    k_vmd_all<<<dim3(VMD_BLOCKS), dim3(512), 0, stream>>>(FPT, U, D);
    k_stageCD<<<dim3(128), dim3(1024), 65536, stream>>>(U);
    k_out0T<<<dim3(32, 8), dim3(256), 0, stream>>>((const float*)U, out);
    k_out1T<<<dim3(128), dim3(256), 0, stream>>>((const float*)U, out);
    k_omega<<<dim3(1), dim3(256), 0, stream>>>(D, out);
}